// Round 2
// baseline (627.882 us; speedup 1.0000x reference)
//
#include <hip/hip_runtime.h>
#include <hip/hip_bf16.h>

// Problem constants
#define S 128
#define BATCH 8192
#define E 300
#define KPAD 640            // 2E=600 padded to multiple of 32
#define H1 2048
#define H2 2048
#define CLS 1221
#define CPAD 1280           // padded N for last GEMM
#define PADTOK 1

typedef __bf16 bf16x8 __attribute__((ext_vector_type(8)));
typedef float f32x4 __attribute__((ext_vector_type(4)));

__device__ __forceinline__ ushort f2b(float f) {
  unsigned int i = __float_as_uint(f);
  unsigned int r = (i + 0x7FFFu + ((i >> 16) & 1u)) >> 16;
  return (ushort)r;
}
__device__ __forceinline__ void async16(const void* g, void* l) {
  __builtin_amdgcn_global_load_lds(
      (__attribute__((address_space(1))) void*)(void*)(const_cast<void*>(g)),
      (__attribute__((address_space(3))) void*)l, 16, 0, 0);
}

// ---------------------------------------------------------------------------
// Stage 0a: W1 fp32 [2048,600] -> bf16 [2048,640] (zeros in tail)
__global__ __launch_bounds__(256) void cvt_w1(const float* __restrict__ W1,
                                              ushort* __restrict__ W1p) {
  int idx = blockIdx.x * 256 + threadIdx.x;
  if (idx >= H1 * KPAD) return;
  int h = idx / KPAD;
  int k = idx - h * KPAD;
  W1p[idx] = (k < 2 * E) ? f2b(W1[h * (2 * E) + k]) : (ushort)0;
}

// Stage 0b: W2 fp32 [2048,2048] -> bf16
__global__ __launch_bounds__(256) void cvt_w2(const float* __restrict__ W2,
                                              ushort* __restrict__ W2b) {
  int idx = blockIdx.x * 256 + threadIdx.x;
  if (idx >= H2 * H1) return;
  W2b[idx] = f2b(W2[idx]);
}

// Stage 0c: W_out fp32 [1221,2048] -> bf16 [1280,2048] (zeros in tail rows)
__global__ __launch_bounds__(256) void cvt_wout(const float* __restrict__ W,
                                                ushort* __restrict__ Wp) {
  int idx = blockIdx.x * 256 + threadIdx.x;
  if (idx >= CPAD * H2) return;
  int n = idx >> 11;          // /2048
  Wp[idx] = (n < CLS) ? f2b(W[idx]) : (ushort)0;
}

// ---------------------------------------------------------------------------
// Stage 1: embedding gather + first-token + masked mean -> feat [B, 640] bf16
// One block (128 threads = 2 waves) per sentence. emb is fp32.
__global__ __launch_bounds__(128) void embed_kernel(const int* __restrict__ x,
                                                    const float* __restrict__ emb,
                                                    ushort* __restrict__ feat) {
  __shared__ int toks[S];
  __shared__ unsigned long long masks[2];
  const int b = blockIdx.x;
  const int t = threadIdx.x;

  int tok = x[(size_t)t * BATCH + b];   // x[s=t][b]
  toks[t] = tok;
  unsigned long long m = __ballot(tok != PADTOK);
  if ((t & 63) == 0) masks[t >> 6] = m;
  __syncthreads();

  unsigned long long m0 = masks[0], m1 = masks[1];
  int last;
  if (m1)      last = 127 - __clzll(m1);
  else if (m0) last = 63 - __clzll(m0);
  else         last = S - 1;            // all-pad: ref argmax gives last=S-1
  const float inv = 1.0f / (float)(last + 1);

  // element pairs: p0 = t (elems 2t,2t+1), p1 = t+128 (valid if < 150)
  const int p0 = t;
  const int p1 = t + 128;
  const bool has2 = (p1 < E / 2);       // t < 22
  float a0 = 0.f, a1 = 0.f, a2 = 0.f, a3 = 0.f;
  for (int s = 0; s <= last; s++) {
    const float* row = emb + (size_t)toks[s] * E;
    float2 u = *(const float2*)(row + 2 * p0);
    a0 += u.x; a1 += u.y;
    if (has2) {
      float2 v = *(const float2*)(row + 2 * p1);
      a2 += v.x; a3 += v.y;
    }
  }

  ushort* fr = feat + (size_t)b * KPAD;
  // mean half: feat[b][300 + e]
  fr[E + 2 * p0]     = f2b(a0 * inv);
  fr[E + 2 * p0 + 1] = f2b(a1 * inv);
  if (has2) {
    fr[E + 2 * p1]     = f2b(a2 * inv);
    fr[E + 2 * p1 + 1] = f2b(a3 * inv);
  }
  // first-token half
  const float* r0 = emb + (size_t)toks[0] * E;
  float2 u0 = *(const float2*)(r0 + 2 * p0);
  fr[2 * p0]     = f2b(u0.x);
  fr[2 * p0 + 1] = f2b(u0.y);
  if (has2) {
    float2 v0 = *(const float2*)(r0 + 2 * p1);
    fr[2 * p1]     = f2b(v0.x);
    fr[2 * p1 + 1] = f2b(v0.y);
  }
  // zero the K padding 600..639
  if (t < (KPAD - 2 * E) / 2) {
    ushort2 z; z.x = 0; z.y = 0;
    *(ushort2*)(fr + 2 * E + 2 * t) = z;
  }
}

// ---------------------------------------------------------------------------
// GEMM: C[M,N] = act(A[M,K] * B[N,K]^T + bias), A/B bf16, fp32 accum via MFMA.
// 128x128 tile, BK=32, 256 threads (4 waves, 2x2 of 64x64), m97 structure.
// FP32OUT: store fp32 (final layer) vs bf16 (hidden layers).
#define BM 128
#define BN 128
#define BK 32

template <bool RELU, bool NGUARD, bool FP32OUT>
__global__ __launch_bounds__(256) void gemm_bt(const ushort* __restrict__ A,
                                               const ushort* __restrict__ B,
                                               const float* __restrict__ bias,
                                               void* __restrict__ Cv,
                                               int K, int lda, int ldb, int ldc,
                                               int Nreal) {
  __shared__ __align__(16) ushort lA[BM * BK];  // 8 KB, row stride 32 elems
  __shared__ __align__(16) ushort lB[BN * BK];  // 8 KB

  const int tid = threadIdx.x;
  const int wave = tid >> 6;
  const int lane = tid & 63;
  const int m0 = blockIdx.y * BM;
  const int n0 = blockIdx.x * BN;
  const int wm = (wave >> 1) * 64;   // wave sub-tile origin in tile
  const int wn = (wave & 1) * 64;

  f32x4 acc[4][4];
#pragma unroll
  for (int i = 0; i < 4; i++)
#pragma unroll
    for (int j = 0; j < 4; j++) acc[i][j] = (f32x4){0.f, 0.f, 0.f, 0.f};

  // staging geometry: instruction i covers rows i*16 + lane/4, 16B chunk (lane%4)
  const int srow = lane >> 2;        // 0..15
  const int skel = (lane & 3) * 8;   // element offset in row

  const int lrow = lane & 15;        // fragment row/col within 16
  const int lkel = (lane >> 4) * 8;  // fragment k offset

  for (int k0 = 0; k0 < K; k0 += BK) {
#pragma unroll
    for (int j = 0; j < 2; j++) {
      const int i = wave * 2 + j;
      const int row = i * 16 + srow;
      async16(A + (size_t)(m0 + row) * lda + k0 + skel, (void*)&lA[i * 512]);
      async16(B + (size_t)(n0 + row) * ldb + k0 + skel, (void*)&lB[i * 512]);
    }
    __syncthreads();

    bf16x8 af[4], bfr[4];
#pragma unroll
    for (int mi = 0; mi < 4; mi++)
      af[mi] = *(const bf16x8*)&lA[(wm + mi * 16 + lrow) * BK + lkel];
#pragma unroll
    for (int ni = 0; ni < 4; ni++)
      bfr[ni] = *(const bf16x8*)&lB[(wn + ni * 16 + lrow) * BK + lkel];
#pragma unroll
    for (int mi = 0; mi < 4; mi++)
#pragma unroll
      for (int ni = 0; ni < 4; ni++)
        acc[mi][ni] = __builtin_amdgcn_mfma_f32_16x16x32_bf16(af[mi], bfr[ni],
                                                              acc[mi][ni], 0, 0, 0);
    __syncthreads();
  }

  // Epilogue. C/D layout: col = lane&15, row = (lane>>4)*4 + reg  [verified]
  const int row_in = (lane >> 4) * 4;
  const int col_in = lane & 15;
#pragma unroll
  for (int ni = 0; ni < 4; ni++) {
    const int col = n0 + wn + ni * 16 + col_in;
    const bool ok = (!NGUARD) || (col < Nreal);
    const float bv = ok ? bias[col] : 0.f;
#pragma unroll
    for (int mi = 0; mi < 4; mi++) {
#pragma unroll
      for (int r = 0; r < 4; r++) {
        const int row = m0 + wm + mi * 16 + row_in + r;
        float v = acc[mi][ni][r] + bv;
        if (RELU) v = fmaxf(v, 0.f);
        if (ok) {
          if (FP32OUT) ((float*)Cv)[(size_t)row * ldc + col] = v;
          else         ((ushort*)Cv)[(size_t)row * ldc + col] = f2b(v);
        }
      }
    }
  }
}

// ---------------------------------------------------------------------------
extern "C" void kernel_launch(void* const* d_in, const int* in_sizes, int n_in,
                              void* d_out, int out_size, void* d_ws, size_t ws_size,
                              hipStream_t stream) {
  const int* x = (const int*)d_in[0];
  const float* emb = (const float*)d_in[1];
  const float* W1 = (const float*)d_in[2];
  const float* b1 = (const float*)d_in[3];
  const float* W2 = (const float*)d_in[4];
  const float* b2 = (const float*)d_in[5];
  const float* Wout = (const float*)d_in[6];
  const float* bout = (const float*)d_in[7];
  float* out = (float*)d_out;

  char* ws = (char*)d_ws;
  ushort* feat = (ushort*)ws;  ws += (size_t)BATCH * KPAD * 2;   // 10.5 MB
  ushort* h1 = (ushort*)ws;    ws += (size_t)BATCH * H1 * 2;     // 33.6 MB
  ushort* h2 = (ushort*)ws;    ws += (size_t)BATCH * H2 * 2;     // 33.6 MB
  ushort* W1p = (ushort*)ws;   ws += (size_t)H1 * KPAD * 2;      // 2.6 MB
  ushort* W2b = (ushort*)ws;   ws += (size_t)H2 * H1 * 2;        // 8.4 MB
  ushort* Woutp = (ushort*)ws; ws += (size_t)CPAD * H2 * 2;      // 5.2 MB

  cvt_w1<<<(H1 * KPAD + 255) / 256, 256, 0, stream>>>(W1, W1p);
  cvt_w2<<<(H2 * H1 + 255) / 256, 256, 0, stream>>>(W2, W2b);
  cvt_wout<<<(CPAD * H2 + 255) / 256, 256, 0, stream>>>(Wout, Woutp);
  embed_kernel<<<BATCH, S, 0, stream>>>(x, emb, feat);

  // L1: feat[8192,640] x W1p[2048,640]^T -> relu -> h1[8192,2048] bf16
  gemm_bt<true, false, false><<<dim3(H1 / BN, BATCH / BM), 256, 0, stream>>>(
      feat, W1p, b1, (void*)h1, KPAD, KPAD, KPAD, H1, H1);
  // L2: h1 x W2b[2048,2048]^T -> relu -> h2 bf16
  gemm_bt<true, false, false><<<dim3(H2 / BN, BATCH / BM), 256, 0, stream>>>(
      h1, W2b, b2, (void*)h2, H1, H1, H1, H2, H2);
  // L3: h2 x Woutp[1280,2048]^T + bias -> out[8192,1221] fp32 (guarded)
  gemm_bt<false, true, true><<<dim3(CPAD / BN, BATCH / BM), 256, 0, stream>>>(
      h2, Woutp, bout, (void*)out, H2, H2, H2, CLS, CLS);
}

// Round 3
// 574.225 us; speedup vs baseline: 1.0934x; 1.0934x over previous
//
#include <hip/hip_runtime.h>
#include <hip/hip_bf16.h>

// Problem constants
#define S 128
#define BATCH 8192
#define E 300
#define KPAD 640            // 2E=600 padded to multiple of 32
#define H1 2048
#define H2 2048
#define CLS 1221
#define CPAD 1280           // padded N for last GEMM
#define PADTOK 1
#define VOCAB 100000

typedef __bf16 bf16x8 __attribute__((ext_vector_type(8)));
typedef float f32x4 __attribute__((ext_vector_type(4)));

__device__ __forceinline__ float b2f(ushort u) {
  union { unsigned int i; float f; } v; v.i = ((unsigned int)u) << 16; return v.f;
}
__device__ __forceinline__ ushort f2b(float f) {
  unsigned int i = __float_as_uint(f);
  unsigned int r = (i + 0x7FFFu + ((i >> 16) & 1u)) >> 16;
  return (ushort)r;
}
__device__ __forceinline__ void async16(const void* g, void* l) {
  __builtin_amdgcn_global_load_lds(
      (__attribute__((address_space(1))) void*)(void*)(const_cast<void*>(g)),
      (__attribute__((address_space(3))) void*)l, 16, 0, 0);
}

// ---------------------------------------------------------------------------
// Stage 0a: W1 fp32 [2048,600] -> bf16 [2048,640] (zeros in tail)
__global__ __launch_bounds__(256) void cvt_w1(const float* __restrict__ W1,
                                              ushort* __restrict__ W1p) {
  int idx = blockIdx.x * 256 + threadIdx.x;
  if (idx >= H1 * KPAD) return;
  int h = idx / KPAD;
  int k = idx - h * KPAD;
  W1p[idx] = (k < 2 * E) ? f2b(W1[h * (2 * E) + k]) : (ushort)0;
}

// Stage 0b: W2 fp32 [2048,2048] -> bf16
__global__ __launch_bounds__(256) void cvt_w2(const float* __restrict__ W2,
                                              ushort* __restrict__ W2b) {
  int idx = blockIdx.x * 256 + threadIdx.x;
  if (idx >= H2 * H1) return;
  W2b[idx] = f2b(W2[idx]);
}

// Stage 0c: W_out fp32 [1221,2048] -> bf16 [1280,2048] (zeros in tail rows)
__global__ __launch_bounds__(256) void cvt_wout(const float* __restrict__ W,
                                                ushort* __restrict__ Wp) {
  int idx = blockIdx.x * 256 + threadIdx.x;
  if (idx >= CPAD * H2) return;
  int n = idx >> 11;          // /2048
  Wp[idx] = (n < CLS) ? f2b(W[idx]) : (ushort)0;
}

// Stage 0d: emb fp32 [100000,300] -> bf16 (element count divisible by 4)
__global__ __launch_bounds__(256) void cvt_emb(const float* __restrict__ Ein,
                                               ushort* __restrict__ Eb) {
  int idx = blockIdx.x * 256 + threadIdx.x;   // quad index
  const int total = VOCAB * E / 4;            // 7,500,000
  if (idx >= total) return;
  float4 v = ((const float4*)Ein)[idx];
  ushort4 o;
  o.x = f2b(v.x); o.y = f2b(v.y); o.z = f2b(v.z); o.w = f2b(v.w);
  ((ushort4*)Eb)[idx] = o;
}

// ---------------------------------------------------------------------------
// Stage 1: embedding gather + first-token + masked mean -> feat [B, 640] bf16
// One block (128 threads = 2 waves) per sentence; emb is the bf16 copy.
// s-loop unrolled x8 with batched loads for memory-level parallelism.
__global__ __launch_bounds__(128) void embed_kernel(const int* __restrict__ x,
                                                    const ushort* __restrict__ emb,
                                                    ushort* __restrict__ feat) {
  __shared__ int toks[S];
  __shared__ unsigned long long masks[2];
  const int b = blockIdx.x;
  const int t = threadIdx.x;

  int tok = x[(size_t)t * BATCH + b];   // x[s=t][b]
  toks[t] = tok;
  unsigned long long m = __ballot(tok != PADTOK);
  if ((t & 63) == 0) masks[t >> 6] = m;
  __syncthreads();

  unsigned long long m0 = masks[0], m1 = masks[1];
  int last;
  if (m1)      last = 127 - __clzll(m1);
  else if (m0) last = 63 - __clzll(m0);
  else         last = S - 1;            // all-pad: ref argmax gives last=S-1
  const int n = last + 1;
  const float inv = 1.0f / (float)n;

  // element pairs: p0 = t (elems 2t,2t+1), p1 = t+128 (valid if < 150)
  const int p0 = t;
  const int p1 = t + 128;
  const bool has2 = (p1 < E / 2);       // t < 22
  float a0 = 0.f, a1 = 0.f, a2 = 0.f, a3 = 0.f;

  int s = 0;
  for (; s + 8 <= n; s += 8) {
    const ushort* r[8];
#pragma unroll
    for (int j = 0; j < 8; j++) r[j] = emb + (size_t)toks[s + j] * E;
    ushort2 u[8];
#pragma unroll
    for (int j = 0; j < 8; j++) u[j] = *(const ushort2*)(r[j] + 2 * p0);
    ushort2 v[8];
    if (has2) {
#pragma unroll
      for (int j = 0; j < 8; j++) v[j] = *(const ushort2*)(r[j] + 2 * p1);
    }
#pragma unroll
    for (int j = 0; j < 8; j++) { a0 += b2f(u[j].x); a1 += b2f(u[j].y); }
    if (has2) {
#pragma unroll
      for (int j = 0; j < 8; j++) { a2 += b2f(v[j].x); a3 += b2f(v[j].y); }
    }
  }
  for (; s < n; s++) {
    const ushort* row = emb + (size_t)toks[s] * E;
    ushort2 u = *(const ushort2*)(row + 2 * p0);
    a0 += b2f(u.x); a1 += b2f(u.y);
    if (has2) {
      ushort2 v0 = *(const ushort2*)(row + 2 * p1);
      a2 += b2f(v0.x); a3 += b2f(v0.y);
    }
  }

  ushort* fr = feat + (size_t)b * KPAD;
  // mean half: feat[b][300 + e]
  ushort2 mo;
  mo.x = f2b(a0 * inv); mo.y = f2b(a1 * inv);
  *(ushort2*)(fr + E + 2 * p0) = mo;
  if (has2) {
    ushort2 mo2;
    mo2.x = f2b(a2 * inv); mo2.y = f2b(a3 * inv);
    *(ushort2*)(fr + E + 2 * p1) = mo2;
  }
  // first-token half: direct bf16 copy
  const ushort* r0 = emb + (size_t)toks[0] * E;
  *(ushort2*)(fr + 2 * p0) = *(const ushort2*)(r0 + 2 * p0);
  if (has2) *(ushort2*)(fr + 2 * p1) = *(const ushort2*)(r0 + 2 * p1);
  // zero the K padding 600..639
  if (t < (KPAD - 2 * E) / 2) {
    ushort2 z; z.x = 0; z.y = 0;
    *(ushort2*)(fr + 2 * E + 2 * t) = z;
  }
}

// ---------------------------------------------------------------------------
// GEMM: C[M,N] = act(A[M,K] * B[N,K]^T + bias), A/B bf16, fp32 accum via MFMA.
// 128x128 tile, BK=32, 256 threads (4 waves, 2x2 of 64x64), m97 structure.
// FP32OUT: store fp32 (final layer) vs bf16 (hidden layers).
#define BM 128
#define BN 128
#define BK 32

template <bool RELU, bool NGUARD, bool FP32OUT>
__global__ __launch_bounds__(256) void gemm_bt(const ushort* __restrict__ A,
                                               const ushort* __restrict__ B,
                                               const float* __restrict__ bias,
                                               void* __restrict__ Cv,
                                               int K, int lda, int ldb, int ldc,
                                               int Nreal) {
  __shared__ __align__(16) ushort lA[BM * BK];  // 8 KB, row stride 32 elems
  __shared__ __align__(16) ushort lB[BN * BK];  // 8 KB

  const int tid = threadIdx.x;
  const int wave = tid >> 6;
  const int lane = tid & 63;
  const int m0 = blockIdx.y * BM;
  const int n0 = blockIdx.x * BN;
  const int wm = (wave >> 1) * 64;   // wave sub-tile origin in tile
  const int wn = (wave & 1) * 64;

  f32x4 acc[4][4];
#pragma unroll
  for (int i = 0; i < 4; i++)
#pragma unroll
    for (int j = 0; j < 4; j++) acc[i][j] = (f32x4){0.f, 0.f, 0.f, 0.f};

  // staging geometry: instruction i covers rows i*16 + lane/4, 16B chunk (lane%4)
  const int srow = lane >> 2;        // 0..15
  const int skel = (lane & 3) * 8;   // element offset in row

  const int lrow = lane & 15;        // fragment row/col within 16
  const int lkel = (lane >> 4) * 8;  // fragment k offset

  for (int k0 = 0; k0 < K; k0 += BK) {
#pragma unroll
    for (int j = 0; j < 2; j++) {
      const int i = wave * 2 + j;
      const int row = i * 16 + srow;
      async16(A + (size_t)(m0 + row) * lda + k0 + skel, (void*)&lA[i * 512]);
      async16(B + (size_t)(n0 + row) * ldb + k0 + skel, (void*)&lB[i * 512]);
    }
    __syncthreads();

    bf16x8 af[4], bfr[4];
#pragma unroll
    for (int mi = 0; mi < 4; mi++)
      af[mi] = *(const bf16x8*)&lA[(wm + mi * 16 + lrow) * BK + lkel];
#pragma unroll
    for (int ni = 0; ni < 4; ni++)
      bfr[ni] = *(const bf16x8*)&lB[(wn + ni * 16 + lrow) * BK + lkel];
#pragma unroll
    for (int mi = 0; mi < 4; mi++)
#pragma unroll
      for (int ni = 0; ni < 4; ni++)
        acc[mi][ni] = __builtin_amdgcn_mfma_f32_16x16x32_bf16(af[mi], bfr[ni],
                                                              acc[mi][ni], 0, 0, 0);
    __syncthreads();
  }

  // Epilogue. C/D layout: col = lane&15, row = (lane>>4)*4 + reg  [verified]
  const int row_in = (lane >> 4) * 4;
  const int col_in = lane & 15;
#pragma unroll
  for (int ni = 0; ni < 4; ni++) {
    const int col = n0 + wn + ni * 16 + col_in;
    const bool ok = (!NGUARD) || (col < Nreal);
    const float bv = ok ? bias[col] : 0.f;
#pragma unroll
    for (int mi = 0; mi < 4; mi++) {
#pragma unroll
      for (int r = 0; r < 4; r++) {
        const int row = m0 + wm + mi * 16 + row_in + r;
        float v = acc[mi][ni][r] + bv;
        if (RELU) v = fmaxf(v, 0.f);
        if (ok) {
          if (FP32OUT) ((float*)Cv)[(size_t)row * ldc + col] = v;
          else         ((ushort*)Cv)[(size_t)row * ldc + col] = f2b(v);
        }
      }
    }
  }
}

// ---------------------------------------------------------------------------
extern "C" void kernel_launch(void* const* d_in, const int* in_sizes, int n_in,
                              void* d_out, int out_size, void* d_ws, size_t ws_size,
                              hipStream_t stream) {
  const int* x = (const int*)d_in[0];
  const float* emb = (const float*)d_in[1];
  const float* W1 = (const float*)d_in[2];
  const float* b1 = (const float*)d_in[3];
  const float* W2 = (const float*)d_in[4];
  const float* b2 = (const float*)d_in[5];
  const float* Wout = (const float*)d_in[6];
  const float* bout = (const float*)d_in[7];
  float* out = (float*)d_out;

  char* ws = (char*)d_ws;
  ushort* feat = (ushort*)ws;  ws += (size_t)BATCH * KPAD * 2;   // 10.5 MB
  ushort* h1 = (ushort*)ws;    ws += (size_t)BATCH * H1 * 2;     // 33.6 MB
  ushort* h2 = (ushort*)ws;    ws += (size_t)BATCH * H2 * 2;     // 33.6 MB
  ushort* W1p = (ushort*)ws;   ws += (size_t)H1 * KPAD * 2;      // 2.6 MB
  ushort* W2b = (ushort*)ws;   ws += (size_t)H2 * H1 * 2;        // 8.4 MB
  ushort* Woutp = (ushort*)ws; ws += (size_t)CPAD * H2 * 2;      // 5.2 MB
  ushort* Eb = (ushort*)ws;    ws += (size_t)VOCAB * E * 2;      // 60 MB

  cvt_emb<<<(VOCAB * E / 4 + 255) / 256, 256, 0, stream>>>(emb, Eb);
  cvt_w1<<<(H1 * KPAD + 255) / 256, 256, 0, stream>>>(W1, W1p);
  cvt_w2<<<(H2 * H1 + 255) / 256, 256, 0, stream>>>(W2, W2b);
  cvt_wout<<<(CPAD * H2 + 255) / 256, 256, 0, stream>>>(Wout, Woutp);
  embed_kernel<<<BATCH, S, 0, stream>>>(x, Eb, feat);

  // L1: feat[8192,640] x W1p[2048,640]^T -> relu -> h1[8192,2048] bf16
  gemm_bt<true, false, false><<<dim3(H1 / BN, BATCH / BM), 256, 0, stream>>>(
      feat, W1p, b1, (void*)h1, KPAD, KPAD, KPAD, H1, H1);
  // L2: h1 x W2b[2048,2048]^T -> relu -> h2 bf16
  gemm_bt<true, false, false><<<dim3(H2 / BN, BATCH / BM), 256, 0, stream>>>(
      h1, W2b, b2, (void*)h2, H1, H1, H1, H2, H2);
  // L3: h2 x Woutp[1280,2048]^T + bias -> out[8192,1221] fp32 (guarded)
  gemm_bt<false, true, true><<<dim3(CPAD / BN, BATCH / BM), 256, 0, stream>>>(
      h2, Woutp, bout, (void*)out, H2, H2, H2, CLS, CLS);
}

// Round 4
// 543.714 us; speedup vs baseline: 1.1548x; 1.0561x over previous
//
#include <hip/hip_runtime.h>
#include <hip/hip_bf16.h>

// Problem constants
#define S 128
#define BATCH 8192
#define E 300
#define KPAD 640            // 2E=600 padded to multiple of 32
#define H1 2048
#define H2 2048
#define CLS 1221
#define CPAD 1280           // padded N for last GEMM
#define PADTOK 1
#define VOCAB 100000

typedef __bf16 bf16x8 __attribute__((ext_vector_type(8)));
typedef float f32x4 __attribute__((ext_vector_type(4)));

__device__ __forceinline__ float b2f(ushort u) {
  union { unsigned int i; float f; } v; v.i = ((unsigned int)u) << 16; return v.f;
}
__device__ __forceinline__ ushort f2b(float f) {
  unsigned int i = __float_as_uint(f);
  unsigned int r = (i + 0x7FFFu + ((i >> 16) & 1u)) >> 16;
  return (ushort)r;
}
__device__ __forceinline__ void async16(const void* g, void* l) {
  __builtin_amdgcn_global_load_lds(
      (__attribute__((address_space(1))) void*)(void*)(const_cast<void*>(g)),
      (__attribute__((address_space(3))) void*)l, 16, 0, 0);
}

// ---------------------------------------------------------------------------
// Fused preprocessing: emb->bf16, W1->bf16 pad, W2->bf16, Wout->bf16 pad,
// x transpose. One quad (4 elements) per thread.
#define NQ_EMB (VOCAB * E / 4)          // 7,500,000
#define NQ_W1  (H1 * KPAD / 4)          // 327,680
#define NQ_W2  (H1 * H2 / 4)            // 1,048,576
#define NQ_WO  (CPAD * H2 / 4)          // 655,360
#define NQ_XT  (S * BATCH / 4)          // 262,144
#define NQ_TOT (NQ_EMB + NQ_W1 + NQ_W2 + NQ_WO + NQ_XT)

__global__ __launch_bounds__(256) void cvt_all(const float* __restrict__ Ein,
                                               ushort* __restrict__ Eb,
                                               const float* __restrict__ W1,
                                               ushort* __restrict__ W1p,
                                               const float* __restrict__ W2,
                                               ushort* __restrict__ W2b,
                                               const float* __restrict__ Wout,
                                               ushort* __restrict__ Woutp,
                                               const int* __restrict__ x,
                                               int* __restrict__ xT) {
  int q = blockIdx.x * 256 + threadIdx.x;
  if (q < NQ_EMB) {
    float4 v = ((const float4*)Ein)[q];
    ushort4 o;
    o.x = f2b(v.x); o.y = f2b(v.y); o.z = f2b(v.z); o.w = f2b(v.w);
    ((ushort4*)Eb)[q] = o;
    return;
  }
  q -= NQ_EMB;
  if (q < NQ_W1) {
    int row = q / 160;                 // 640/4 quads per padded row
    int k0 = (q - row * 160) * 4;
    ushort4 o; o.x = 0; o.y = 0; o.z = 0; o.w = 0;
    if (k0 < 2 * E) {
      float4 v = *(const float4*)(W1 + (size_t)row * (2 * E) + k0);
      o.x = f2b(v.x); o.y = f2b(v.y); o.z = f2b(v.z); o.w = f2b(v.w);
    }
    ((ushort4*)W1p)[q] = o;
    return;
  }
  q -= NQ_W1;
  if (q < NQ_W2) {
    float4 v = ((const float4*)W2)[q];
    ushort4 o;
    o.x = f2b(v.x); o.y = f2b(v.y); o.z = f2b(v.z); o.w = f2b(v.w);
    ((ushort4*)W2b)[q] = o;
    return;
  }
  q -= NQ_W2;
  if (q < NQ_WO) {
    int n = (q * 4) >> 11;             // row in padded [1280, 2048]
    ushort4 o; o.x = 0; o.y = 0; o.z = 0; o.w = 0;
    if (n < CLS) {
      float4 v = ((const float4*)Wout)[q];
      o.x = f2b(v.x); o.y = f2b(v.y); o.z = f2b(v.z); o.w = f2b(v.w);
    }
    ((ushort4*)Woutp)[q] = o;
    return;
  }
  q -= NQ_WO;
  if (q < NQ_XT) {
    int b = q >> 5;                    // 32 quads per sentence (128 tokens)
    int t4 = (q & 31) * 4;
    int4 o;
    o.x = x[(size_t)(t4 + 0) * BATCH + b];
    o.y = x[(size_t)(t4 + 1) * BATCH + b];
    o.z = x[(size_t)(t4 + 2) * BATCH + b];
    o.w = x[(size_t)(t4 + 3) * BATCH + b];
    ((int4*)xT)[q] = o;
  }
}

// ---------------------------------------------------------------------------
// Stage 1: embedding gather + first-token + masked mean -> feat [B, 640] bf16
// One block (128 threads = 2 waves) per sentence; emb is the bf16 copy.
// Byte-offset table in LDS, x16 unrolled batched loads, balanced waves.
__global__ __launch_bounds__(128) void embed_kernel(const int* __restrict__ xT,
                                                    const ushort* __restrict__ emb,
                                                    ushort* __restrict__ feat) {
  __shared__ uint offs[S];
  __shared__ unsigned long long masks[2];
  const int b = blockIdx.x;
  const int t = threadIdx.x;

  int tok = xT[b * S + t];             // coalesced
  offs[t] = (uint)tok * 600u;          // byte offset into bf16 emb table
  unsigned long long m = __ballot(tok != PADTOK);
  if ((t & 63) == 0) masks[t >> 6] = m;
  __syncthreads();

  unsigned long long m0 = masks[0], m1 = masks[1];
  int last;
  if (m1)      last = 127 - __clzll(m1);
  else if (m0) last = 63 - __clzll(m0);
  else         last = S - 1;           // all-pad: ref argmax gives last=S-1
  const int n = last + 1;
  const float inv = 1.0f / (float)n;

  // balanced pair mapping: wave0 -> pairs 0..74, wave1 -> pairs 75..149
  const int lane = t & 63;
  const int q0 = (t < 64) ? t : (11 + t);   // 0..63 / 75..138
  const bool has2 = (lane < 11);            // +64 -> 64..74 / 139..149
  const int q1 = q0 + 64;
  const uint off0 = 4u * (uint)q0;          // byte offset of pair within row
  const uint off1 = 4u * (uint)q1;
  const char* base = (const char*)emb;

  float a0 = 0.f, a1 = 0.f, a2 = 0.f, a3 = 0.f;
  int s = 0;
  for (; s + 16 <= n; s += 16) {
    uint o[16];
#pragma unroll
    for (int j = 0; j < 16; j++) o[j] = offs[s + j];
    ushort2 u[16];
#pragma unroll
    for (int j = 0; j < 16; j++) u[j] = *(const ushort2*)(base + (o[j] + off0));
    ushort2 v[16];
    if (has2) {
#pragma unroll
      for (int j = 0; j < 16; j++) v[j] = *(const ushort2*)(base + (o[j] + off1));
    }
#pragma unroll
    for (int j = 0; j < 16; j++) { a0 += b2f(u[j].x); a1 += b2f(u[j].y); }
    if (has2) {
#pragma unroll
      for (int j = 0; j < 16; j++) { a2 += b2f(v[j].x); a3 += b2f(v[j].y); }
    }
  }
  for (; s < n; s++) {
    uint o = offs[s];
    ushort2 u = *(const ushort2*)(base + (o + off0));
    a0 += b2f(u.x); a1 += b2f(u.y);
    if (has2) {
      ushort2 v0 = *(const ushort2*)(base + (o + off1));
      a2 += b2f(v0.x); a3 += b2f(v0.y);
    }
  }

  ushort* fr = feat + (size_t)b * KPAD;
  // mean half: feat[b][300 + 2q]
  ushort2 mo; mo.x = f2b(a0 * inv); mo.y = f2b(a1 * inv);
  *(ushort2*)(fr + E + 2 * q0) = mo;
  if (has2) {
    ushort2 mo2; mo2.x = f2b(a2 * inv); mo2.y = f2b(a3 * inv);
    *(ushort2*)(fr + E + 2 * q1) = mo2;
  }
  // first-token half: direct bf16 copy
  const uint o0 = offs[0];
  *(ushort2*)(fr + 2 * q0) = *(const ushort2*)(base + (o0 + off0));
  if (has2) *(ushort2*)(fr + 2 * q1) = *(const ushort2*)(base + (o0 + off1));
  // zero the K padding 600..639
  if (t < 20) {
    ushort2 z; z.x = 0; z.y = 0;
    *(ushort2*)(fr + 2 * E + 2 * t) = z;
  }
}

// ---------------------------------------------------------------------------
// GEMM: C[M,N] = act(A[M,K] * B[N,K]^T + bias), A/B bf16, fp32 accum via MFMA.
// 128x128 tile, BK=32, 256 threads (4 waves, 2x2 of 64x64), m97 structure.
#define BM 128
#define BN 128
#define BK 32

template <bool RELU, bool NGUARD, bool FP32OUT>
__global__ __launch_bounds__(256) void gemm_bt(const ushort* __restrict__ A,
                                               const ushort* __restrict__ B,
                                               const float* __restrict__ bias,
                                               void* __restrict__ Cv,
                                               int K, int lda, int ldb, int ldc,
                                               int Nreal) {
  __shared__ __align__(16) ushort lA[BM * BK];  // 8 KB, row stride 32 elems
  __shared__ __align__(16) ushort lB[BN * BK];  // 8 KB

  const int tid = threadIdx.x;
  const int wave = tid >> 6;
  const int lane = tid & 63;
  const int m0 = blockIdx.y * BM;
  const int n0 = blockIdx.x * BN;
  const int wm = (wave >> 1) * 64;   // wave sub-tile origin in tile
  const int wn = (wave & 1) * 64;

  f32x4 acc[4][4];
#pragma unroll
  for (int i = 0; i < 4; i++)
#pragma unroll
    for (int j = 0; j < 4; j++) acc[i][j] = (f32x4){0.f, 0.f, 0.f, 0.f};

  // staging geometry: instruction i covers rows i*16 + lane/4, 16B chunk (lane%4)
  const int srow = lane >> 2;        // 0..15
  const int skel = (lane & 3) * 8;   // element offset in row

  const int lrow = lane & 15;        // fragment row/col within 16
  const int lkel = (lane >> 4) * 8;  // fragment k offset

  for (int k0 = 0; k0 < K; k0 += BK) {
#pragma unroll
    for (int j = 0; j < 2; j++) {
      const int i = wave * 2 + j;
      const int row = i * 16 + srow;
      async16(A + (size_t)(m0 + row) * lda + k0 + skel, (void*)&lA[i * 512]);
      async16(B + (size_t)(n0 + row) * ldb + k0 + skel, (void*)&lB[i * 512]);
    }
    __syncthreads();

    bf16x8 af[4], bfr[4];
#pragma unroll
    for (int mi = 0; mi < 4; mi++)
      af[mi] = *(const bf16x8*)&lA[(wm + mi * 16 + lrow) * BK + lkel];
#pragma unroll
    for (int ni = 0; ni < 4; ni++)
      bfr[ni] = *(const bf16x8*)&lB[(wn + ni * 16 + lrow) * BK + lkel];
#pragma unroll
    for (int mi = 0; mi < 4; mi++)
#pragma unroll
      for (int ni = 0; ni < 4; ni++)
        acc[mi][ni] = __builtin_amdgcn_mfma_f32_16x16x32_bf16(af[mi], bfr[ni],
                                                              acc[mi][ni], 0, 0, 0);
    __syncthreads();
  }

  // Epilogue. C/D layout: col = lane&15, row = (lane>>4)*4 + reg  [verified]
  const int row_in = (lane >> 4) * 4;
  const int col_in = lane & 15;
#pragma unroll
  for (int ni = 0; ni < 4; ni++) {
    const int col = n0 + wn + ni * 16 + col_in;
    const bool ok = (!NGUARD) || (col < Nreal);
    const float bv = ok ? bias[col] : 0.f;
#pragma unroll
    for (int mi = 0; mi < 4; mi++) {
#pragma unroll
      for (int r = 0; r < 4; r++) {
        const int row = m0 + wm + mi * 16 + row_in + r;
        float v = acc[mi][ni][r] + bv;
        if (RELU) v = fmaxf(v, 0.f);
        if (ok) {
          if (FP32OUT) ((float*)Cv)[(size_t)row * ldc + col] = v;
          else         ((ushort*)Cv)[(size_t)row * ldc + col] = f2b(v);
        }
      }
    }
  }
}

// ---------------------------------------------------------------------------
extern "C" void kernel_launch(void* const* d_in, const int* in_sizes, int n_in,
                              void* d_out, int out_size, void* d_ws, size_t ws_size,
                              hipStream_t stream) {
  const int* x = (const int*)d_in[0];
  const float* emb = (const float*)d_in[1];
  const float* W1 = (const float*)d_in[2];
  const float* b1 = (const float*)d_in[3];
  const float* W2 = (const float*)d_in[4];
  const float* b2 = (const float*)d_in[5];
  const float* Wout = (const float*)d_in[6];
  const float* bout = (const float*)d_in[7];
  float* out = (float*)d_out;

  char* ws = (char*)d_ws;
  ushort* feat = (ushort*)ws;  ws += (size_t)BATCH * KPAD * 2;   // 10.5 MB
  ushort* h1 = (ushort*)ws;    ws += (size_t)BATCH * H1 * 2;     // 33.6 MB
  ushort* h2 = (ushort*)ws;    ws += (size_t)BATCH * H2 * 2;     // 33.6 MB
  ushort* W1p = (ushort*)ws;   ws += (size_t)H1 * KPAD * 2;      // 2.6 MB
  ushort* W2b = (ushort*)ws;   ws += (size_t)H2 * H1 * 2;        // 8.4 MB
  ushort* Woutp = (ushort*)ws; ws += (size_t)CPAD * H2 * 2;      // 5.2 MB
  ushort* Eb = (ushort*)ws;    ws += (size_t)VOCAB * E * 2;      // 60 MB
  int* xT = (int*)ws;          ws += (size_t)S * BATCH * 4;      // 4 MB

  cvt_all<<<(NQ_TOT + 255) / 256, 256, 0, stream>>>(emb, Eb, W1, W1p, W2, W2b,
                                                    Wout, Woutp, x, xT);
  embed_kernel<<<BATCH, S, 0, stream>>>(xT, Eb, feat);

  // L1: feat[8192,640] x W1p[2048,640]^T -> relu -> h1[8192,2048] bf16
  gemm_bt<true, false, false><<<dim3(H1 / BN, BATCH / BM), 256, 0, stream>>>(
      feat, W1p, b1, (void*)h1, KPAD, KPAD, KPAD, H1, H1);
  // L2: h1 x W2b[2048,2048]^T -> relu -> h2 bf16
  gemm_bt<true, false, false><<<dim3(H2 / BN, BATCH / BM), 256, 0, stream>>>(
      h1, W2b, b2, (void*)h2, H1, H1, H1, H2, H2);
  // L3: h2 x Woutp[1280,2048]^T + bias -> out[8192,1221] fp32 (guarded)
  gemm_bt<false, true, true><<<dim3(CPAD / BN, BATCH / BM), 256, 0, stream>>>(
      h2, Woutp, bout, (void*)out, H2, H2, H2, CLS, CLS);
}

// Round 5
// 501.529 us; speedup vs baseline: 1.2519x; 1.0841x over previous
//
#include <hip/hip_runtime.h>
#include <hip/hip_bf16.h>

// Problem constants
#define S 128
#define BATCH 8192
#define E 300
#define KPAD 640            // 2E=600 padded to multiple of 64
#define H1 2048
#define H2 2048
#define CLS 1221
#define CPAD 1280           // padded N for last GEMM
#define PADTOK 1
#define VOCAB 100000

typedef __bf16 bf16x8 __attribute__((ext_vector_type(8)));
typedef float f32x16 __attribute__((ext_vector_type(16)));

__device__ __forceinline__ float b2f(ushort u) {
  union { unsigned int i; float f; } v; v.i = ((unsigned int)u) << 16; return v.f;
}
__device__ __forceinline__ ushort f2b(float f) {
  unsigned int i = __float_as_uint(f);
  unsigned int r = (i + 0x7FFFu + ((i >> 16) & 1u)) >> 16;
  return (ushort)r;
}
__device__ __forceinline__ void async16(const void* g, void* l) {
  __builtin_amdgcn_global_load_lds(
      (__attribute__((address_space(1))) void*)(void*)(const_cast<void*>(g)),
      (__attribute__((address_space(3))) void*)l, 16, 0, 0);
}

// ---------------------------------------------------------------------------
// Fused preprocessing: emb->bf16, W1->bf16 pad, W2->bf16, Wout->bf16 pad,
// x transpose. One quad (4 elements) per thread.
#define NQ_EMB (VOCAB * E / 4)          // 7,500,000
#define NQ_W1  (H1 * KPAD / 4)          // 327,680
#define NQ_W2  (H1 * H2 / 4)            // 1,048,576
#define NQ_WO  (CPAD * H2 / 4)          // 655,360
#define NQ_XT  (S * BATCH / 4)          // 262,144
#define NQ_TOT (NQ_EMB + NQ_W1 + NQ_W2 + NQ_WO + NQ_XT)

__global__ __launch_bounds__(256) void cvt_all(const float* __restrict__ Ein,
                                               ushort* __restrict__ Eb,
                                               const float* __restrict__ W1,
                                               ushort* __restrict__ W1p,
                                               const float* __restrict__ W2,
                                               ushort* __restrict__ W2b,
                                               const float* __restrict__ Wout,
                                               ushort* __restrict__ Woutp,
                                               const int* __restrict__ x,
                                               int* __restrict__ xT) {
  int q = blockIdx.x * 256 + threadIdx.x;
  if (q < NQ_EMB) {
    float4 v = ((const float4*)Ein)[q];
    ushort4 o;
    o.x = f2b(v.x); o.y = f2b(v.y); o.z = f2b(v.z); o.w = f2b(v.w);
    ((ushort4*)Eb)[q] = o;
    return;
  }
  q -= NQ_EMB;
  if (q < NQ_W1) {
    int row = q / 160;                 // 640/4 quads per padded row
    int k0 = (q - row * 160) * 4;
    ushort4 o; o.x = 0; o.y = 0; o.z = 0; o.w = 0;
    if (k0 < 2 * E) {
      float4 v = *(const float4*)(W1 + (size_t)row * (2 * E) + k0);
      o.x = f2b(v.x); o.y = f2b(v.y); o.z = f2b(v.z); o.w = f2b(v.w);
    }
    ((ushort4*)W1p)[q] = o;
    return;
  }
  q -= NQ_W1;
  if (q < NQ_W2) {
    float4 v = ((const float4*)W2)[q];
    ushort4 o;
    o.x = f2b(v.x); o.y = f2b(v.y); o.z = f2b(v.z); o.w = f2b(v.w);
    ((ushort4*)W2b)[q] = o;
    return;
  }
  q -= NQ_W2;
  if (q < NQ_WO) {
    int n = (q * 4) >> 11;             // row in padded [1280, 2048]
    ushort4 o; o.x = 0; o.y = 0; o.z = 0; o.w = 0;
    if (n < CLS) {
      float4 v = ((const float4*)Wout)[q];
      o.x = f2b(v.x); o.y = f2b(v.y); o.z = f2b(v.z); o.w = f2b(v.w);
    }
    ((ushort4*)Woutp)[q] = o;
    return;
  }
  q -= NQ_WO;
  if (q < NQ_XT) {
    int b = q >> 5;                    // 32 quads per sentence (128 tokens)
    int t4 = (q & 31) * 4;
    int4 o;
    o.x = x[(size_t)(t4 + 0) * BATCH + b];
    o.y = x[(size_t)(t4 + 1) * BATCH + b];
    o.z = x[(size_t)(t4 + 2) * BATCH + b];
    o.w = x[(size_t)(t4 + 3) * BATCH + b];
    ((int4*)xT)[q] = o;
  }
}

// ---------------------------------------------------------------------------
// Stage 1: embedding gather + first-token + masked mean -> feat [B, 640] bf16
// One block (128 threads = 2 waves) per sentence; emb is the bf16 copy.
// Byte-offset table in LDS, x16 unrolled batched loads, balanced waves.
__global__ __launch_bounds__(128) void embed_kernel(const int* __restrict__ xT,
                                                    const ushort* __restrict__ emb,
                                                    ushort* __restrict__ feat) {
  __shared__ uint offs[S];
  __shared__ unsigned long long masks[2];
  const int b = blockIdx.x;
  const int t = threadIdx.x;

  int tok = xT[b * S + t];             // coalesced
  offs[t] = (uint)tok * 600u;          // byte offset into bf16 emb table
  unsigned long long m = __ballot(tok != PADTOK);
  if ((t & 63) == 0) masks[t >> 6] = m;
  __syncthreads();

  unsigned long long m0 = masks[0], m1 = masks[1];
  int last;
  if (m1)      last = 127 - __clzll(m1);
  else if (m0) last = 63 - __clzll(m0);
  else         last = S - 1;           // all-pad: ref argmax gives last=S-1
  const int n = last + 1;
  const float inv = 1.0f / (float)n;

  // balanced pair mapping: wave0 -> pairs 0..74, wave1 -> pairs 75..149
  const int lane = t & 63;
  const int q0 = (t < 64) ? t : (11 + t);   // 0..63 / 75..138
  const bool has2 = (lane < 11);            // +64 -> 64..74 / 139..149
  const int q1 = q0 + 64;
  const uint off0 = 4u * (uint)q0;          // byte offset of pair within row
  const uint off1 = 4u * (uint)q1;
  const char* base = (const char*)emb;

  float a0 = 0.f, a1 = 0.f, a2 = 0.f, a3 = 0.f;
  int s = 0;
  for (; s + 16 <= n; s += 16) {
    uint o[16];
#pragma unroll
    for (int j = 0; j < 16; j++) o[j] = offs[s + j];
    ushort2 u[16];
#pragma unroll
    for (int j = 0; j < 16; j++) u[j] = *(const ushort2*)(base + (o[j] + off0));
    ushort2 v[16];
    if (has2) {
#pragma unroll
      for (int j = 0; j < 16; j++) v[j] = *(const ushort2*)(base + (o[j] + off1));
    }
#pragma unroll
    for (int j = 0; j < 16; j++) { a0 += b2f(u[j].x); a1 += b2f(u[j].y); }
    if (has2) {
#pragma unroll
      for (int j = 0; j < 16; j++) { a2 += b2f(v[j].x); a3 += b2f(v[j].y); }
    }
  }
  for (; s < n; s++) {
    uint o = offs[s];
    ushort2 u = *(const ushort2*)(base + (o + off0));
    a0 += b2f(u.x); a1 += b2f(u.y);
    if (has2) {
      ushort2 v0 = *(const ushort2*)(base + (o + off1));
      a2 += b2f(v0.x); a3 += b2f(v0.y);
    }
  }

  ushort* fr = feat + (size_t)b * KPAD;
  // mean half: feat[b][300 + 2q]
  ushort2 mo; mo.x = f2b(a0 * inv); mo.y = f2b(a1 * inv);
  *(ushort2*)(fr + E + 2 * q0) = mo;
  if (has2) {
    ushort2 mo2; mo2.x = f2b(a2 * inv); mo2.y = f2b(a3 * inv);
    *(ushort2*)(fr + E + 2 * q1) = mo2;
  }
  // first-token half: direct bf16 copy
  const uint o0 = offs[0];
  *(ushort2*)(fr + 2 * q0) = *(const ushort2*)(base + (o0 + off0));
  if (has2) *(ushort2*)(fr + 2 * q1) = *(const ushort2*)(base + (o0 + off1));
  // zero the K padding 600..639
  if (t < 20) {
    ushort2 z; z.x = 0; z.y = 0;
    *(ushort2*)(fr + 2 * E + 2 * t) = z;
  }
}

// ---------------------------------------------------------------------------
// GEMM: C[M,N] = act(A[M,K] * B[N,K]^T + bias), A/B bf16, fp32 MFMA accum.
// 128x128 tile, BK=64, 256 threads (4 waves, 2x2 of 64x64), 32x32x16 MFMA.
// LDS layout XOR-swizzled at 16B-chunk granularity via the global_load_lds
// source mapping: slot(row,kc) = row*8 + (kc ^ (row&7)) -> conflict-free
// ds_read_b128 (each quarter-wave tiles all 32 banks exactly 4x = minimum).
#define BM 128
#define BN 128
#define BK 64

template <bool RELU, bool NGUARD, bool FP32OUT>
__global__ __launch_bounds__(256) void gemm_bt(const ushort* __restrict__ A,
                                               const ushort* __restrict__ B,
                                               const float* __restrict__ bias,
                                               void* __restrict__ Cv,
                                               int K, int lda, int ldb, int ldc,
                                               int Nreal) {
  __shared__ __align__(16) ushort lA[BM * BK];  // 16 KB
  __shared__ __align__(16) ushort lB[BN * BK];  // 16 KB

  const int tid = threadIdx.x;
  const int wave = tid >> 6;
  const int lane = tid & 63;
  const int m0 = blockIdx.y * BM;
  const int n0 = blockIdx.x * BN;
  const int wm = (wave >> 1) * 64;   // wave sub-tile origin in tile
  const int wn = (wave & 1) * 64;

  f32x16 acc[2][2];
#pragma unroll
  for (int i = 0; i < 2; i++)
#pragma unroll
    for (int j = 0; j < 2; j++)
#pragma unroll
      for (int r = 0; r < 16; r++) acc[i][j][r] = 0.f;

  // staging: 16 instrs of 64 slots (8 rows x 8 chunks each); wave does 4.
  // slot i in group: row = g*8 + (i>>3), chunk c = i&7, kc = c ^ (row&7).
  const int srow8 = lane >> 3;                 // row within 8-row group
  const int kcw = (lane & 7) ^ srow8;          // swizzled source k-chunk

  // fragment read geometry (32x32x16): row = lane&31, k = (lane>>5)*8 + j
  const int lr = lane & 31;
  const int lk = lane >> 5;                    // 0/1
  const int lx = lr & 7;                       // for swizzle

  for (int k0 = 0; k0 < K; k0 += BK) {
#pragma unroll
    for (int j = 0; j < 4; j++) {
      const int g = wave * 4 + j;
      const int row = g * 8 + srow8;
      async16(A + (size_t)(m0 + row) * lda + k0 + kcw * 8, (void*)&lA[g * 512]);
      async16(B + (size_t)(n0 + row) * ldb + k0 + kcw * 8, (void*)&lB[g * 512]);
    }
    __syncthreads();

#pragma unroll
    for (int ks = 0; ks < 4; ks++) {
      const int kc = ks * 2 + lk;
      bf16x8 af[2], bfr[2];
#pragma unroll
      for (int mi = 0; mi < 2; mi++) {
        const int row = wm + mi * 32 + lr;
        af[mi] = *(const bf16x8*)&lA[(row * 8 + (kc ^ lx)) * 8];
      }
#pragma unroll
      for (int ni = 0; ni < 2; ni++) {
        const int row = wn + ni * 32 + lr;
        bfr[ni] = *(const bf16x8*)&lB[(row * 8 + (kc ^ lx)) * 8];
      }
#pragma unroll
      for (int mi = 0; mi < 2; mi++)
#pragma unroll
        for (int ni = 0; ni < 2; ni++)
          acc[mi][ni] = __builtin_amdgcn_mfma_f32_32x32x16_bf16(
              af[mi], bfr[ni], acc[mi][ni], 0, 0, 0);
    }
    __syncthreads();
  }

  // Epilogue. 32x32 C/D layout: col = lane&31,
  // row = (reg&3) + 8*(reg>>2) + 4*(lane>>5)   [verified m74/m101]
#pragma unroll
  for (int ni = 0; ni < 2; ni++) {
    const int col = n0 + wn + ni * 32 + lr;
    const bool ok = (!NGUARD) || (col < Nreal);
    const float bv = ok ? bias[col] : 0.f;
#pragma unroll
    for (int mi = 0; mi < 2; mi++) {
#pragma unroll
      for (int r = 0; r < 16; r++) {
        const int row = m0 + wm + mi * 32 + (r & 3) + 8 * (r >> 2) + 4 * lk;
        float v = acc[mi][ni][r] + bv;
        if (RELU) v = fmaxf(v, 0.f);
        if (ok) {
          if (FP32OUT) ((float*)Cv)[(size_t)row * ldc + col] = v;
          else         ((ushort*)Cv)[(size_t)row * ldc + col] = f2b(v);
        }
      }
    }
  }
}

// ---------------------------------------------------------------------------
extern "C" void kernel_launch(void* const* d_in, const int* in_sizes, int n_in,
                              void* d_out, int out_size, void* d_ws, size_t ws_size,
                              hipStream_t stream) {
  const int* x = (const int*)d_in[0];
  const float* emb = (const float*)d_in[1];
  const float* W1 = (const float*)d_in[2];
  const float* b1 = (const float*)d_in[3];
  const float* W2 = (const float*)d_in[4];
  const float* b2 = (const float*)d_in[5];
  const float* Wout = (const float*)d_in[6];
  const float* bout = (const float*)d_in[7];
  float* out = (float*)d_out;

  char* ws = (char*)d_ws;
  ushort* feat = (ushort*)ws;  ws += (size_t)BATCH * KPAD * 2;   // 10.5 MB
  ushort* h1 = (ushort*)ws;    ws += (size_t)BATCH * H1 * 2;     // 33.6 MB
  ushort* h2 = (ushort*)ws;    ws += (size_t)BATCH * H2 * 2;     // 33.6 MB
  ushort* W1p = (ushort*)ws;   ws += (size_t)H1 * KPAD * 2;      // 2.6 MB
  ushort* W2b = (ushort*)ws;   ws += (size_t)H2 * H1 * 2;        // 8.4 MB
  ushort* Woutp = (ushort*)ws; ws += (size_t)CPAD * H2 * 2;      // 5.2 MB
  ushort* Eb = (ushort*)ws;    ws += (size_t)VOCAB * E * 2;      // 60 MB
  int* xT = (int*)ws;          ws += (size_t)S * BATCH * 4;      // 4 MB

  cvt_all<<<(NQ_TOT + 255) / 256, 256, 0, stream>>>(emb, Eb, W1, W1p, W2, W2b,
                                                    Wout, Woutp, x, xT);
  embed_kernel<<<BATCH, S, 0, stream>>>(xT, Eb, feat);

  // L1: feat[8192,640] x W1p[2048,640]^T -> relu -> h1[8192,2048] bf16
  gemm_bt<true, false, false><<<dim3(H1 / BN, BATCH / BM), 256, 0, stream>>>(
      feat, W1p, b1, (void*)h1, KPAD, KPAD, KPAD, H1, H1);
  // L2: h1 x W2b[2048,2048]^T -> relu -> h2 bf16
  gemm_bt<true, false, false><<<dim3(H2 / BN, BATCH / BM), 256, 0, stream>>>(
      h1, W2b, b2, (void*)h2, H1, H1, H1, H2, H2);
  // L3: h2 x Woutp[1280,2048]^T + bias -> out[8192,1221] fp32 (guarded)
  gemm_bt<false, true, true><<<dim3(CPAD / BN, BATCH / BM), 256, 0, stream>>>(
      h2, Woutp, bout, (void*)out, H2, H2, H2, CLS, CLS);
}